// Round 5
// baseline (272.541 us; speedup 1.0000x reference)
//
#include <hip/hip_runtime.h>
#include <math.h>

#define BB 32
#define NN 128
#define DD 64
#define EE (NN*NN)          // 16384
#define EPSI 1e-5f

typedef __attribute__((ext_vector_type(8))) short bf16x8;   // 8 bf16 (4 VGPRs)
typedef __attribute__((ext_vector_type(4))) float f32x4;

__device__ __forceinline__ short f2bf(float f) {
    union { float f; unsigned u; } v; v.f = f;
    unsigned u = v.u;
    unsigned r = (u + 0x7FFFu + ((u >> 16) & 1u)) >> 16;    // RNE
    return (short)r;
}
__device__ __forceinline__ float elu(float v) {
    return v > 0.f ? v : __expf(v) - 1.f;     // v_exp_f32 path
}

// ---------------------------------------------------------------------------
// k_fold: Mbf[d][k] = bf16( sum_o Wp[d][128+o] * We[o][k] )  (fc_e folded into fc_proj)
//         wbf[k]    = bf16( sum_o Wa[128+o]    * We[o][k] )  (fc_e folded into attn_fc)
__global__ void k_fold(const float* __restrict__ Wp, const float* __restrict__ We,
                       const float* __restrict__ Wa,
                       short* __restrict__ Mbf, short* __restrict__ wbf)
{
    int t = blockIdx.x * 256 + threadIdx.x;   // 0..4095
    int d = t >> 6, k = t & 63;
    float acc = 0.f;
    for (int o = 0; o < DD; ++o)
        acc += Wp[d*192 + 128 + o] * We[o*DD + k];
    Mbf[d*DD + k] = f2bf(acc);
    if (d == 0) {
        float aw = 0.f;
        for (int o = 0; o < DD; ++o)
            aw += Wa[128 + o] * We[o*DD + k];
        wbf[k] = f2bf(aw);
    }
}

// ---------------------------------------------------------------------------
// k_node: per (b,n) row: z_h = x @ Wh^T ; P_src = z_h @ Wp[:, :64]^T ;
//         P_dst = z_h @ Wp[:, 64:128]^T ; s = z_h . Wa[:64] ; t = z_h . Wa[64:128]
__global__ void k_node(const float* __restrict__ x, const float* __restrict__ Wh,
                       const float* __restrict__ Wp, const float* __restrict__ Wa,
                       float* __restrict__ zh, float* __restrict__ Ps,
                       float* __restrict__ Pd, float* __restrict__ sO,
                       float* __restrict__ tO)
{
    int row = blockIdx.x;          // b*N + n
    int d = threadIdx.x;           // 0..63
    __shared__ float xr[DD];
    __shared__ float zr[DD];
    xr[d] = x[row*DD + d];
    __syncthreads();
    float acc = 0.f;
#pragma unroll
    for (int k = 0; k < DD; ++k) acc += xr[k] * Wh[d*DD + k];
    zr[d] = acc;
    zh[row*DD + d] = acc;
    __syncthreads();
    float a0 = 0.f, a1 = 0.f;
#pragma unroll
    for (int o = 0; o < DD; ++o) {
        float z = zr[o];
        a0 += Wp[d*192 + o]      * z;
        a1 += Wp[d*192 + 64 + o] * z;
    }
    Ps[row*DD + d] = a0;
    Pd[row*DD + d] = a1;
    float sv = zr[d] * Wa[d];
    float tv = zr[d] * Wa[64 + d];
#pragma unroll
    for (int off = 32; off; off >>= 1) {
        sv += __shfl_xor(sv, off);
        tv += __shfl_xor(tv, off);
    }
    if (d == 0) { sO[row] = sv; tO[row] = tv; }
}

// ---------------------------------------------------------------------------
// k_edge v5 (bf16 MFMA, register-only, no LDS, no barriers):
//   z = edge @ M^T + Ps[b,j] + Pd[b,i] -> BN(per-e over b,d) -> ELU
//   u[b,e] = edge . w  computed as a 5th MFMA B-tile (col0 = w)
// 256 threads = 4 waves; wave w owns channel e = 4*blk + w (32 rows x 64 cols).
// Accumulator initialized with Ps+Pd (C-fragment-layout scalar loads, L2-hot),
// so A-loads / B-loads / P-loads are all concurrently in flight before MFMA.
// BN stats: full-wave shfl reduce directly on fragments.
__global__ __launch_bounds__(256, 4) void k_edge(
    const float* __restrict__ ein,   // (B,E,D)
    const short* __restrict__ Mbf,   // (D,D) bf16
    const short* __restrict__ wbf,   // (D)   bf16
    const float* __restrict__ Ps,    // (B,N,D)
    const float* __restrict__ Pd,    // (B,N,D)
    const float* __restrict__ ge, const float* __restrict__ be,
    float* __restrict__ eout, float* __restrict__ uout)
{
    const int l  = threadIdx.x & 63;
    const int wv = threadIdx.x >> 6;
    const int lr = l & 15;
    const int lg = l >> 4;
    const int e  = blockIdx.x * 4 + wv;
    const int i0 = e >> 7, j0 = e & 127;

    // ---- A loads: 8 float4 (rows b = 16m+lr, k-halves) ----
    float4 ald[2][4];
#pragma unroll
    for (int m = 0; m < 2; ++m) {
        const float* rowp = ein + ((size_t)(16*m + lr)*EE + e)*DD;
        ald[m][0] = *reinterpret_cast<const float4*>(rowp +      lg*8);
        ald[m][1] = *reinterpret_cast<const float4*>(rowp +      lg*8 + 4);
        ald[m][2] = *reinterpret_cast<const float4*>(rowp + 32 + lg*8);
        ald[m][3] = *reinterpret_cast<const float4*>(rowp + 32 + lg*8 + 4);
    }

    // ---- B fragments (M^T, bf16, L2-hot) + w fragment (col0 only) ----
    bf16x8 bfr[4][2];
#pragma unroll
    for (int n = 0; n < 4; ++n)
#pragma unroll
        for (int s = 0; s < 2; ++s)
            bfr[n][s] = *reinterpret_cast<const bf16x8*>(Mbf + (16*n + lr)*DD + s*32 + lg*8);
    const bf16x8 zerov = (bf16x8){0,0,0,0,0,0,0,0};
    bf16x8 wfrag[2];
#pragma unroll
    for (int s = 0; s < 2; ++s)
        wfrag[s] = (lr == 0) ? *reinterpret_cast<const bf16x8*>(wbf + s*32 + lg*8) : zerov;

    // ---- acc init = Ps[b,j0] + Pd[b,i0] in C-fragment layout (L2-hot scalars) ----
    f32x4 acc[2][4];
    f32x4 uacc[2];
#pragma unroll
    for (int m = 0; m < 2; ++m) {
        uacc[m] = (f32x4){0.f, 0.f, 0.f, 0.f};
#pragma unroll
        for (int q = 0; q < 4; ++q) {
            const int b = 16*m + 4*lg + q;
            const float* ps = Ps + ((size_t)(b*NN + j0))*DD + lr;
            const float* pd = Pd + ((size_t)(b*NN + i0))*DD + lr;
#pragma unroll
            for (int n = 0; n < 4; ++n)
                acc[m][n][q] = ps[16*n] + pd[16*n];
        }
    }

    // ---- convert A to bf16, MFMA (16 z-tiles + 4 u-tiles) ----
#pragma unroll
    for (int m = 0; m < 2; ++m) {
        bf16x8 a0, a1;
        a0[0]=f2bf(ald[m][0].x); a0[1]=f2bf(ald[m][0].y); a0[2]=f2bf(ald[m][0].z); a0[3]=f2bf(ald[m][0].w);
        a0[4]=f2bf(ald[m][1].x); a0[5]=f2bf(ald[m][1].y); a0[6]=f2bf(ald[m][1].z); a0[7]=f2bf(ald[m][1].w);
        a1[0]=f2bf(ald[m][2].x); a1[1]=f2bf(ald[m][2].y); a1[2]=f2bf(ald[m][2].z); a1[3]=f2bf(ald[m][2].w);
        a1[4]=f2bf(ald[m][3].x); a1[5]=f2bf(ald[m][3].y); a1[6]=f2bf(ald[m][3].z); a1[7]=f2bf(ald[m][3].w);
#pragma unroll
        for (int n = 0; n < 4; ++n)
            acc[m][n] = __builtin_amdgcn_mfma_f32_16x16x32_bf16(a0, bfr[n][0], acc[m][n], 0, 0, 0);
        uacc[m] = __builtin_amdgcn_mfma_f32_16x16x32_bf16(a0, wfrag[0], uacc[m], 0, 0, 0);
#pragma unroll
        for (int n = 0; n < 4; ++n)
            acc[m][n] = __builtin_amdgcn_mfma_f32_16x16x32_bf16(a1, bfr[n][1], acc[m][n], 0, 0, 0);
        uacc[m] = __builtin_amdgcn_mfma_f32_16x16x32_bf16(a1, wfrag[1], uacc[m], 0, 0, 0);
    }

    // ---- BN stats: full-wave shfl reduce over the 2048 channel elements ----
    float s1 = 0.f, s2 = 0.f;
#pragma unroll
    for (int m = 0; m < 2; ++m)
#pragma unroll
        for (int n = 0; n < 4; ++n)
#pragma unroll
            for (int q = 0; q < 4; ++q) { float v = acc[m][n][q]; s1 += v; s2 += v*v; }
#pragma unroll
    for (int off = 1; off < 64; off <<= 1) {
        s1 += __shfl_xor(s1, off);
        s2 += __shfl_xor(s2, off);
    }
    const float mean = s1 * (1.f/2048.f);
    const float var  = s2 * (1.f/2048.f) - mean*mean;
    const float sc = ge[e] * rsqrtf(var + EPSI);
    const float sh = be[e] - mean*sc;

    // ---- normalize + ELU + store (scalar, L2 merges the 4 n-segments) ----
#pragma unroll
    for (int m = 0; m < 2; ++m)
#pragma unroll
        for (int q = 0; q < 4; ++q) {
            const int b = 16*m + 4*lg + q;
            float* orow = eout + ((size_t)b*EE + e)*DD + lr;
#pragma unroll
            for (int n = 0; n < 4; ++n)
                orow[16*n] = elu(acc[m][n][q]*sc + sh);
        }
    // ---- u store (col0 lanes hold u[b] for b = 16m+4lg+q) ----
    if (lr == 0) {
#pragma unroll
        for (int m = 0; m < 2; ++m)
#pragma unroll
            for (int q = 0; q < 4; ++q)
                uout[(size_t)(16*m + 4*lg + q)*EE + e] = uacc[m][q];
    }
}

// ---------------------------------------------------------------------------
// k_attn: per (b,i): logits = lrelu(s[j] + t[i] + u[b,i*N+j]) -> softmax over j
//         agg[b,i,:] = sum_j attn_j * zh[b,j,:]
__global__ void k_attn(const float* __restrict__ sI, const float* __restrict__ tI,
                       const float* __restrict__ u, const float* __restrict__ zh,
                       float* __restrict__ agg)
{
    int blk = blockIdx.x; int b = blk >> 7, i = blk & 127;
    int l = threadIdx.x;
    __shared__ float at[NN];
    float ti = tI[blk];
    float l0 = sI[b*NN + l]      + ti + u[b*EE + i*NN + l];
    float l1 = sI[b*NN + l + 64] + ti + u[b*EE + i*NN + l + 64];
    l0 = l0 >= 0.f ? l0 : 0.01f*l0;
    l1 = l1 >= 0.f ? l1 : 0.01f*l1;
    float mx = fmaxf(l0, l1);
#pragma unroll
    for (int off = 32; off; off >>= 1) mx = fmaxf(mx, __shfl_xor(mx, off));
    float e0 = __expf(l0 - mx), e1 = __expf(l1 - mx);
    float sm = e0 + e1;
#pragma unroll
    for (int off = 32; off; off >>= 1) sm += __shfl_xor(sm, off);
    float inv = 1.f / sm;
    at[l]      = e0 * inv;
    at[l + 64] = e1 * inv;
    __syncthreads();
    float acc = 0.f;
    for (int j = 0; j < NN; ++j) acc += at[j] * zh[(b*NN + j)*DD + l];
    agg[(b*NN + i)*DD + l] = acc;
}

// ---------------------------------------------------------------------------
// k_vbn: vertex BN (channel i over b,d) + residual + ELU
__global__ void k_vbn(const float* __restrict__ agg, const float* __restrict__ xres,
                      const float* __restrict__ gv, const float* __restrict__ bv,
                      float* __restrict__ xout)
{
    int i = blockIdx.x, t = threadIdx.x;
    float vals[8];
    float s1 = 0.f, s2 = 0.f;
#pragma unroll
    for (int q = 0; q < 8; ++q) {
        int m = t + 256*q; int b = m >> 6, d = m & 63;
        float v = agg[(b*NN + i)*DD + d];
        vals[q] = v; s1 += v; s2 += v*v;
    }
#pragma unroll
    for (int off = 1; off < 64; off <<= 1) {
        s1 += __shfl_xor(s1, off);
        s2 += __shfl_xor(s2, off);
    }
    __shared__ float r1[4], r2[4];
    int wv = t >> 6;
    if ((t & 63) == 0) { r1[wv] = s1; r2[wv] = s2; }
    __syncthreads();
    s1 = r1[0] + r1[1] + r1[2] + r1[3];
    s2 = r2[0] + r2[1] + r2[2] + r2[3];
    float mean  = s1 * (1.f/2048.f);
    float var   = s2 * (1.f/2048.f) - mean*mean;
    float scale = gv[i] * rsqrtf(var + EPSI);
    float shift = bv[i] - mean*scale;
#pragma unroll
    for (int q = 0; q < 8; ++q) {
        int m = t + 256*q; int b = m >> 6, d = m & 63;
        float v = vals[q]*scale + shift + xres[(b*NN + i)*DD + d];
        xout[(b*NN + i)*DD + d] = v > 0.f ? v : __expf(v) - 1.f;
    }
}

// ---------------------------------------------------------------------------
extern "C" void kernel_launch(void* const* d_in, const int* in_sizes, int n_in,
                              void* d_out, int out_size, void* d_ws, size_t ws_size,
                              hipStream_t stream)
{
    const float* x    = (const float*)d_in[0];
    const float* edge = (const float*)d_in[1];
    const float* Wh1  = (const float*)d_in[2];
    const float* We1  = (const float*)d_in[3];
    const float* Wp1  = (const float*)d_in[4];
    const float* Wa1  = (const float*)d_in[5];
    const float* Wh2  = (const float*)d_in[6];
    const float* We2  = (const float*)d_in[7];
    const float* Wp2  = (const float*)d_in[8];
    const float* Wa2  = (const float*)d_in[9];
    const float* gv1  = (const float*)d_in[10];
    const float* bv1  = (const float*)d_in[11];
    const float* ge1  = (const float*)d_in[12];
    const float* be1  = (const float*)d_in[13];
    const float* gv2  = (const float*)d_in[14];
    const float* bv2  = (const float*)d_in[15];
    const float* ge2  = (const float*)d_in[16];
    const float* be2  = (const float*)d_in[17];

    float* xout = (float*)d_out;                    // (B,N,D)
    float* eout = (float*)d_out + BB*NN*DD;         // (B,E,D) — also layer-1 intermediate

    float* ws  = (float*)d_ws;
    short* Mbf = (short*)ws;  ws += DD*DD/2;        // bf16 M^T (8 KB)
    short* wbf = (short*)ws;  ws += DD/2;           // bf16 w
    float* zh  = ws;  ws += BB*NN*DD;
    float* Ps  = ws;  ws += BB*NN*DD;
    float* Pd  = ws;  ws += BB*NN*DD;
    float* sb  = ws;  ws += BB*NN;
    float* tb  = ws;  ws += BB*NN;
    float* ub  = ws;  ws += BB*EE;
    float* agg = ws;  ws += BB*NN*DD;
    float* x1  = ws;  ws += BB*NN*DD;   // total ~7.4 MB

    // ----- layer 1 -----
    k_fold<<<16, 256, 0, stream>>>(Wp1, We1, Wa1, Mbf, wbf);
    k_node<<<BB*NN, 64, 0, stream>>>(x, Wh1, Wp1, Wa1, zh, Ps, Pd, sb, tb);
    k_edge<<<EE/4, 256, 0, stream>>>(edge, Mbf, wbf, Ps, Pd, ge1, be1, eout, ub);
    k_attn<<<BB*NN, 64, 0, stream>>>(sb, tb, ub, zh, agg);
    k_vbn<<<NN, 256, 0, stream>>>(agg, x, gv1, bv1, x1);
    // ----- layer 2 (k_edge reads/writes eout in place; every wave's reads are
    //               consumed by its MFMAs before its stores, and waves/blocks
    //               own disjoint e-rows) -----
    k_fold<<<16, 256, 0, stream>>>(Wp2, We2, Wa2, Mbf, wbf);
    k_node<<<BB*NN, 64, 0, stream>>>(x1, Wh2, Wp2, Wa2, zh, Ps, Pd, sb, tb);
    k_edge<<<EE/4, 256, 0, stream>>>(eout, Mbf, wbf, Ps, Pd, ge2, be2, eout, ub);
    k_attn<<<BB*NN, 64, 0, stream>>>(sb, tb, ub, zh, agg);
    k_vbn<<<NN, 256, 0, stream>>>(agg, x1, gv2, bv2, xout);
}

// Round 6
// 214.668 us; speedup vs baseline: 1.2696x; 1.2696x over previous
//
#include <hip/hip_runtime.h>
#include <math.h>

#define BB 32
#define NN 128
#define DD 64
#define EE (NN*NN)          // 16384
#define EPSI 1e-5f

typedef __attribute__((ext_vector_type(8))) short bf16x8;   // 8 bf16 (4 VGPRs)
typedef __attribute__((ext_vector_type(4))) float f32x4;
typedef __attribute__((ext_vector_type(4))) short s16x4;

__device__ __forceinline__ short f2bf(float f) {
    union { float f; unsigned u; } v; v.f = f;
    unsigned u = v.u;
    unsigned r = (u + 0x7FFFu + ((u >> 16) & 1u)) >> 16;    // RNE
    return (short)r;
}
__device__ __forceinline__ float elu(float v) {
    return v > 0.f ? v : __expf(v) - 1.f;     // v_exp_f32 path
}

// ---------------------------------------------------------------------------
// k_fold: Mbf[d][k] = bf16( sum_o Wp[d][128+o] * We[o][k] )  (fc_e folded into fc_proj)
//         wbf[k]    = bf16( sum_o Wa[128+o]    * We[o][k] )  (fc_e folded into attn_fc)
__global__ void k_fold(const float* __restrict__ Wp, const float* __restrict__ We,
                       const float* __restrict__ Wa,
                       short* __restrict__ Mbf, short* __restrict__ wbf)
{
    int t = blockIdx.x * 256 + threadIdx.x;   // 0..4095
    int d = t >> 6, k = t & 63;
    float acc = 0.f;
    for (int o = 0; o < DD; ++o)
        acc += Wp[d*192 + 128 + o] * We[o*DD + k];
    Mbf[d*DD + k] = f2bf(acc);
    if (d == 0) {
        float aw = 0.f;
        for (int o = 0; o < DD; ++o)
            aw += Wa[128 + o] * We[o*DD + k];
        wbf[k] = f2bf(aw);
    }
}

// ---------------------------------------------------------------------------
// k_node: per (b,n) row: z_h = x @ Wh^T ; P_src = z_h @ Wp[:, :64]^T ;
//         P_dst = z_h @ Wp[:, 64:128]^T ; s = z_h . Wa[:64] ; t = z_h . Wa[64:128]
__global__ void k_node(const float* __restrict__ x, const float* __restrict__ Wh,
                       const float* __restrict__ Wp, const float* __restrict__ Wa,
                       float* __restrict__ zh, float* __restrict__ Ps,
                       float* __restrict__ Pd, float* __restrict__ sO,
                       float* __restrict__ tO)
{
    int row = blockIdx.x;          // b*N + n
    int d = threadIdx.x;           // 0..63
    __shared__ float xr[DD];
    __shared__ float zr[DD];
    xr[d] = x[row*DD + d];
    __syncthreads();
    float acc = 0.f;
#pragma unroll
    for (int k = 0; k < DD; ++k) acc += xr[k] * Wh[d*DD + k];
    zr[d] = acc;
    zh[row*DD + d] = acc;
    __syncthreads();
    float a0 = 0.f, a1 = 0.f;
#pragma unroll
    for (int o = 0; o < DD; ++o) {
        float z = zr[o];
        a0 += Wp[d*192 + o]      * z;
        a1 += Wp[d*192 + 64 + o] * z;
    }
    Ps[row*DD + d] = a0;
    Pd[row*DD + d] = a1;
    float sv = zr[d] * Wa[d];
    float tv = zr[d] * Wa[64 + d];
#pragma unroll
    for (int off = 32; off; off >>= 1) {
        sv += __shfl_xor(sv, off);
        tv += __shfl_xor(tv, off);
    }
    if (d == 0) { sO[row] = sv; tO[row] = tv; }
}

// ---------------------------------------------------------------------------
// k_edge v6 (bf16 MFMA, templated layouts):
//   z = edge @ M^T + Ps[b,j] + Pd[b,i] -> BN(per-e over b,d) -> ELU
//   u[b,e] = edge . w  via a 5th MFMA B-tile (col0 = w)
// 256 threads = 4 waves; wave wv owns channel e = 4*blk + wv (32 b-rows x 64 d).
// INM: 0 = fp32 (B,E,D) input; 1 = bf16 (E,B,D) dense input (layer-2 fast path)
// OUTM: 0 = fp32 (B,E,D) output (d_out); 1 = bf16 (E,B,D) dense output (intermediate)
// Per-wave-private LDS repack ([32][68] fp32) gives coalesced P-add + stores;
// no __syncthreads needed (no cross-wave LDS sharing).
template <int INM, int OUTM>
__global__ __launch_bounds__(256, 4) void k_edge(
    const void* __restrict__ einv,
    const short* __restrict__ Mbf,   // (D,D) bf16
    const short* __restrict__ wbf,   // (D)   bf16
    const float* __restrict__ Ps,    // (B,N,D)
    const float* __restrict__ Pd,    // (B,N,D)
    const float* __restrict__ ge, const float* __restrict__ be,
    void* __restrict__ eoutv, float* __restrict__ uout)
{
    __shared__ float zl[4][32][68];
    const int l  = threadIdx.x & 63;
    const int wv = threadIdx.x >> 6;
    const int lr = l & 15;
    const int lg = l >> 4;
    const int e  = blockIdx.x * 4 + wv;
    const int i0 = e >> 7, j0 = e & 127;
    float (*Z)[68] = zl[wv];

    // ---- A fragments ----
    bf16x8 afr[2][2];                 // [m][k-half]
    if constexpr (INM == 0) {
        const float* ein = (const float*)einv;
#pragma unroll
        for (int m = 0; m < 2; ++m) {
            const float* rowp = ein + ((size_t)(16*m + lr)*EE + e)*DD;
            const float4 v0 = *reinterpret_cast<const float4*>(rowp +      lg*8);
            const float4 v1 = *reinterpret_cast<const float4*>(rowp +      lg*8 + 4);
            const float4 v2 = *reinterpret_cast<const float4*>(rowp + 32 + lg*8);
            const float4 v3 = *reinterpret_cast<const float4*>(rowp + 32 + lg*8 + 4);
            afr[m][0][0]=f2bf(v0.x); afr[m][0][1]=f2bf(v0.y); afr[m][0][2]=f2bf(v0.z); afr[m][0][3]=f2bf(v0.w);
            afr[m][0][4]=f2bf(v1.x); afr[m][0][5]=f2bf(v1.y); afr[m][0][6]=f2bf(v1.z); afr[m][0][7]=f2bf(v1.w);
            afr[m][1][0]=f2bf(v2.x); afr[m][1][1]=f2bf(v2.y); afr[m][1][2]=f2bf(v2.z); afr[m][1][3]=f2bf(v2.w);
            afr[m][1][4]=f2bf(v3.x); afr[m][1][5]=f2bf(v3.y); afr[m][1][6]=f2bf(v3.z); afr[m][1][7]=f2bf(v3.w);
        }
    } else {
        const short* ein = (const short*)einv + (size_t)e*BB*DD;   // dense channel block
#pragma unroll
        for (int m = 0; m < 2; ++m)
#pragma unroll
            for (int s = 0; s < 2; ++s)
                afr[m][s] = *reinterpret_cast<const bf16x8*>(ein + (16*m + lr)*DD + s*32 + lg*8);
    }

    // ---- B fragments (M^T, bf16, L2-hot) + w fragment (col0 only) ----
    bf16x8 bfr[4][2];
#pragma unroll
    for (int n = 0; n < 4; ++n)
#pragma unroll
        for (int s = 0; s < 2; ++s)
            bfr[n][s] = *reinterpret_cast<const bf16x8*>(Mbf + (16*n + lr)*DD + s*32 + lg*8);
    const bf16x8 zerov = (bf16x8){0,0,0,0,0,0,0,0};
    bf16x8 wfrag[2];
#pragma unroll
    for (int s = 0; s < 2; ++s)
        wfrag[s] = (lr == 0) ? *reinterpret_cast<const bf16x8*>(wbf + s*32 + lg*8) : zerov;

    // ---- MFMA: 16 z-tiles + 4 u-tiles ----
    f32x4 acc[2][4];
    f32x4 uacc[2];
#pragma unroll
    for (int m = 0; m < 2; ++m) {
        uacc[m] = (f32x4){0.f, 0.f, 0.f, 0.f};
#pragma unroll
        for (int n = 0; n < 4; ++n)
            acc[m][n] = (f32x4){0.f, 0.f, 0.f, 0.f};
    }
#pragma unroll
    for (int m = 0; m < 2; ++m) {
#pragma unroll
        for (int n = 0; n < 4; ++n)
            acc[m][n] = __builtin_amdgcn_mfma_f32_16x16x32_bf16(afr[m][0], bfr[n][0], acc[m][n], 0, 0, 0);
        uacc[m] = __builtin_amdgcn_mfma_f32_16x16x32_bf16(afr[m][0], wfrag[0], uacc[m], 0, 0, 0);
#pragma unroll
        for (int n = 0; n < 4; ++n)
            acc[m][n] = __builtin_amdgcn_mfma_f32_16x16x32_bf16(afr[m][1], bfr[n][1], acc[m][n], 0, 0, 0);
        uacc[m] = __builtin_amdgcn_mfma_f32_16x16x32_bf16(afr[m][1], wfrag[1], uacc[m], 0, 0, 0);
    }

    // ---- C fragments -> LDS (row = 16m + 4lg + q, col = 16n + lr) ----
#pragma unroll
    for (int m = 0; m < 2; ++m)
#pragma unroll
        for (int n = 0; n < 4; ++n)
#pragma unroll
            for (int q = 0; q < 4; ++q)
                Z[16*m + 4*lg + q][16*n + lr] = acc[m][n][q];

    // ---- P-add (coalesced float4, L2-hot) + BN stats ----
    float s1 = 0.f, s2 = 0.f;
#pragma unroll
    for (int it = 0; it < 8; ++it) {
        const int b = lg + 4*it;
        float4 z = *reinterpret_cast<float4*>(&Z[b][lr*4]);
        const float4 ps = *reinterpret_cast<const float4*>(Ps + ((size_t)(b*NN + j0))*DD + lr*4);
        const float4 pd = *reinterpret_cast<const float4*>(Pd + ((size_t)(b*NN + i0))*DD + lr*4);
        z.x += ps.x + pd.x; z.y += ps.y + pd.y;
        z.z += ps.z + pd.z; z.w += ps.w + pd.w;
        s1 += z.x + z.y + z.z + z.w;
        s2 += z.x*z.x + z.y*z.y + z.z*z.z + z.w*z.w;
        *reinterpret_cast<float4*>(&Z[b][lr*4]) = z;
    }
#pragma unroll
    for (int off = 1; off < 64; off <<= 1) {
        s1 += __shfl_xor(s1, off);
        s2 += __shfl_xor(s2, off);
    }
    const float mean = s1 * (1.f/2048.f);
    const float var  = s2 * (1.f/2048.f) - mean*mean;
    const float sc = ge[e] * rsqrtf(var + EPSI);
    const float sh = be[e] - mean*sc;

    // ---- normalize + ELU + store ----
    if constexpr (OUTM == 0) {
        float* eout = (float*)eoutv;
#pragma unroll
        for (int it = 0; it < 8; ++it) {
            const int b = lg + 4*it;
            float4 z = *reinterpret_cast<float4*>(&Z[b][lr*4]);
            z.x = elu(z.x*sc + sh);
            z.y = elu(z.y*sc + sh);
            z.z = elu(z.z*sc + sh);
            z.w = elu(z.w*sc + sh);
            *reinterpret_cast<float4*>(eout + ((size_t)b*EE + e)*DD + lr*4) = z;
        }
    } else {
        short* eout = (short*)eoutv + (size_t)e*BB*DD;   // dense channel block
#pragma unroll
        for (int it = 0; it < 8; ++it) {
            const int b = 4*it + lg;                      // 512B-contiguous per instr
            const int c0 = lr*4;
            float4 z = *reinterpret_cast<float4*>(&Z[b][c0]);
            s16x4 o;
            o[0] = f2bf(elu(z.x*sc + sh));
            o[1] = f2bf(elu(z.y*sc + sh));
            o[2] = f2bf(elu(z.z*sc + sh));
            o[3] = f2bf(elu(z.w*sc + sh));
            *reinterpret_cast<s16x4*>(eout + b*DD + c0) = o;
        }
    }

    // ---- u store (col0 lanes hold u[b] for b = 16m+4lg+q) ----
    if (lr == 0) {
#pragma unroll
        for (int m = 0; m < 2; ++m)
#pragma unroll
            for (int q = 0; q < 4; ++q)
                uout[(size_t)(16*m + 4*lg + q)*EE + e] = uacc[m][q];
    }
}

// ---------------------------------------------------------------------------
// k_attn: per (b,i): logits = lrelu(s[j] + t[i] + u[b,i*N+j]) -> softmax over j
//         agg[b,i,:] = sum_j attn_j * zh[b,j,:]
__global__ void k_attn(const float* __restrict__ sI, const float* __restrict__ tI,
                       const float* __restrict__ u, const float* __restrict__ zh,
                       float* __restrict__ agg)
{
    int blk = blockIdx.x; int b = blk >> 7, i = blk & 127;
    int l = threadIdx.x;
    __shared__ float at[NN];
    float ti = tI[blk];
    float l0 = sI[b*NN + l]      + ti + u[b*EE + i*NN + l];
    float l1 = sI[b*NN + l + 64] + ti + u[b*EE + i*NN + l + 64];
    l0 = l0 >= 0.f ? l0 : 0.01f*l0;
    l1 = l1 >= 0.f ? l1 : 0.01f*l1;
    float mx = fmaxf(l0, l1);
#pragma unroll
    for (int off = 32; off; off >>= 1) mx = fmaxf(mx, __shfl_xor(mx, off));
    float e0 = __expf(l0 - mx), e1 = __expf(l1 - mx);
    float sm = e0 + e1;
#pragma unroll
    for (int off = 32; off; off >>= 1) sm += __shfl_xor(sm, off);
    float inv = 1.f / sm;
    at[l]      = e0 * inv;
    at[l + 64] = e1 * inv;
    __syncthreads();
    float acc = 0.f;
    for (int j = 0; j < NN; ++j) acc += at[j] * zh[(b*NN + j)*DD + l];
    agg[(b*NN + i)*DD + l] = acc;
}

// ---------------------------------------------------------------------------
// k_vbn: vertex BN (channel i over b,d) + residual + ELU
__global__ void k_vbn(const float* __restrict__ agg, const float* __restrict__ xres,
                      const float* __restrict__ gv, const float* __restrict__ bv,
                      float* __restrict__ xout)
{
    int i = blockIdx.x, t = threadIdx.x;
    float vals[8];
    float s1 = 0.f, s2 = 0.f;
#pragma unroll
    for (int q = 0; q < 8; ++q) {
        int m = t + 256*q; int b = m >> 6, d = m & 63;
        float v = agg[(b*NN + i)*DD + d];
        vals[q] = v; s1 += v; s2 += v*v;
    }
#pragma unroll
    for (int off = 1; off < 64; off <<= 1) {
        s1 += __shfl_xor(s1, off);
        s2 += __shfl_xor(s2, off);
    }
    __shared__ float r1[4], r2[4];
    int wv = t >> 6;
    if ((t & 63) == 0) { r1[wv] = s1; r2[wv] = s2; }
    __syncthreads();
    s1 = r1[0] + r1[1] + r1[2] + r1[3];
    s2 = r2[0] + r2[1] + r2[2] + r2[3];
    float mean  = s1 * (1.f/2048.f);
    float var   = s2 * (1.f/2048.f) - mean*mean;
    float scale = gv[i] * rsqrtf(var + EPSI);
    float shift = bv[i] - mean*scale;
#pragma unroll
    for (int q = 0; q < 8; ++q) {
        int m = t + 256*q; int b = m >> 6, d = m & 63;
        float v = vals[q]*scale + shift + xres[(b*NN + i)*DD + d];
        xout[(b*NN + i)*DD + d] = v > 0.f ? v : __expf(v) - 1.f;
    }
}

// ---------------------------------------------------------------------------
extern "C" void kernel_launch(void* const* d_in, const int* in_sizes, int n_in,
                              void* d_out, int out_size, void* d_ws, size_t ws_size,
                              hipStream_t stream)
{
    const float* x    = (const float*)d_in[0];
    const float* edge = (const float*)d_in[1];
    const float* Wh1  = (const float*)d_in[2];
    const float* We1  = (const float*)d_in[3];
    const float* Wp1  = (const float*)d_in[4];
    const float* Wa1  = (const float*)d_in[5];
    const float* Wh2  = (const float*)d_in[6];
    const float* We2  = (const float*)d_in[7];
    const float* Wp2  = (const float*)d_in[8];
    const float* Wa2  = (const float*)d_in[9];
    const float* gv1  = (const float*)d_in[10];
    const float* bv1  = (const float*)d_in[11];
    const float* ge1  = (const float*)d_in[12];
    const float* be1  = (const float*)d_in[13];
    const float* gv2  = (const float*)d_in[14];
    const float* bv2  = (const float*)d_in[15];
    const float* ge2  = (const float*)d_in[16];
    const float* be2  = (const float*)d_in[17];

    float* xout = (float*)d_out;                    // (B,N,D)
    float* eout = (float*)d_out + BB*NN*DD;         // (B,E,D) final edge output

    float* ws  = (float*)d_ws;
    short* Mbf = (short*)ws;  ws += DD*DD/2;        // bf16 M^T (8 KB)
    short* wbf = (short*)ws;  ws += DD/2;           // bf16 w
    float* zh  = ws;  ws += BB*NN*DD;
    float* Ps  = ws;  ws += BB*NN*DD;
    float* Pd  = ws;  ws += BB*NN*DD;
    float* sb  = ws;  ws += BB*NN;
    float* tb  = ws;  ws += BB*NN;
    float* ub  = ws;  ws += BB*EE;
    float* agg = ws;  ws += BB*NN*DD;
    float* x1  = ws;  ws += BB*NN*DD;
    short* e1bf = (short*)ws;                       // (E,B,D) bf16 intermediate (67 MB)
    const size_t need = ((size_t)(ws - (float*)d_ws))*4 + (size_t)EE*BB*DD*2;

    const bool dense = (ws_size >= need);

    // ----- layer 1 -----
    k_fold<<<16, 256, 0, stream>>>(Wp1, We1, Wa1, Mbf, wbf);
    k_node<<<BB*NN, 64, 0, stream>>>(x, Wh1, Wp1, Wa1, zh, Ps, Pd, sb, tb);
    if (dense)
        k_edge<0,1><<<EE/4, 256, 0, stream>>>(edge, Mbf, wbf, Ps, Pd, ge1, be1, e1bf, ub);
    else
        k_edge<0,0><<<EE/4, 256, 0, stream>>>(edge, Mbf, wbf, Ps, Pd, ge1, be1, eout, ub);
    k_attn<<<BB*NN, 64, 0, stream>>>(sb, tb, ub, zh, agg);
    k_vbn<<<NN, 256, 0, stream>>>(agg, x, gv1, bv1, x1);
    // ----- layer 2 -----
    k_fold<<<16, 256, 0, stream>>>(Wp2, We2, Wa2, Mbf, wbf);
    k_node<<<BB*NN, 64, 0, stream>>>(x1, Wh2, Wp2, Wa2, zh, Ps, Pd, sb, tb);
    if (dense)
        k_edge<1,0><<<EE/4, 256, 0, stream>>>(e1bf, Mbf, wbf, Ps, Pd, ge2, be2, eout, ub);
    else  // in-place on eout: each wave's reads precede its writes; disjoint e-rows
        k_edge<0,0><<<EE/4, 256, 0, stream>>>(eout, Mbf, wbf, Ps, Pd, ge2, be2, eout, ub);
    k_attn<<<BB*NN, 64, 0, stream>>>(sb, tb, ub, zh, agg);
    k_vbn<<<NN, 256, 0, stream>>>(agg, x1, gv2, bv2, xout);
}